// Round 9
// baseline (353.554 us; speedup 1.0000x reference)
//
#include <hip/hip_runtime.h>

#define T_SEQ 2048
#define NHEAD 16
#define HS 64

typedef __bf16 bf16x8 __attribute__((ext_vector_type(8)));
typedef float f32x4 __attribute__((ext_vector_type(4)));
typedef short short4v __attribute__((ext_vector_type(4)));

__device__ __forceinline__ unsigned short f2bf(float f) {
  union { float f; unsigned int u; } v; v.f = f;
  return (unsigned short)((v.u + 0x7fffu + ((v.u >> 16) & 1u)) >> 16);
}
__device__ __forceinline__ float bf2f(unsigned short h) {
  union { unsigned int u; float f; } v; v.u = ((unsigned int)h) << 16;
  return v.f;
}
__device__ __forceinline__ bf16x8 ld_bf8(const unsigned short* p) {
  return *(const bf16x8*)p;
}
__device__ __forceinline__ void st_bf8(unsigned short* p, bf16x8 v) {
  *(bf16x8*)p = v;
}
__device__ __forceinline__ bf16x8 cvt8(float4 a, float4 b) {
  bf16x8 r;
  r[0] = (__bf16)a.x; r[1] = (__bf16)a.y; r[2] = (__bf16)a.z; r[3] = (__bf16)a.w;
  r[4] = (__bf16)b.x; r[5] = (__bf16)b.y; r[6] = (__bf16)b.z; r[7] = (__bf16)b.w;
  return r;
}

// C[m,n] = sum_k A[m,k]*B[n,k];  A:[M,K], B:[N,K] row-major.
// af32/bf32: operand element type is float32 (else bf16).
// mode 0: C row-major [M,N] FLOAT32.  mode 1: qkv scatter (N=3072), bf16.
__global__ __launch_bounds__(256, 2) void gemm_bt(
    const void* __restrict__ Av, const void* __restrict__ Bv,
    float* __restrict__ Cout,
    unsigned short* __restrict__ qb, unsigned short* __restrict__ kb,
    unsigned short* __restrict__ vtb,
    int M, int N, int K, int af32, int bf32, int mode) {
  __shared__ unsigned short As[128 * 64];
  __shared__ unsigned short Bs[128 * 64];
  const int tid = threadIdx.x;
  const int wid = tid >> 6, lane = tid & 63;
  const int quad = lane >> 4, l16 = lane & 15;
  const int m0 = blockIdx.y * 128, n0 = blockIdx.x * 128;
  const int wm = (wid >> 1) * 64, wn = (wid & 1) * 64;
  const int row_in = tid >> 3;
  const int col_in = (tid & 7) * 8;
  const float* Agf = (const float*)Av + (size_t)(m0 + row_in) * K + col_in;
  const float* Bgf = (const float*)Bv + (size_t)(n0 + row_in) * K + col_in;
  const unsigned short* Agh = (const unsigned short*)Av + (size_t)(m0 + row_in) * K + col_in;
  const unsigned short* Bgh = (const unsigned short*)Bv + (size_t)(n0 + row_in) * K + col_in;
  f32x4 acc[4][4] = {};
  const int nkt = K >> 6;
  for (int kt = 0; kt < nkt; ++kt) {
    bf16x8 as8[4], bs8[4];
    if (af32) {
      #pragma unroll
      for (int j = 0; j < 4; ++j) {
        const float* p = Agf + (size_t)j * 32 * K + kt * 64;
        as8[j] = cvt8(*(const float4*)p, *(const float4*)(p + 4));
      }
    } else {
      #pragma unroll
      for (int j = 0; j < 4; ++j)
        as8[j] = ld_bf8(Agh + (size_t)j * 32 * K + kt * 64);
    }
    if (bf32) {
      #pragma unroll
      for (int j = 0; j < 4; ++j) {
        const float* p = Bgf + (size_t)j * 32 * K + kt * 64;
        bs8[j] = cvt8(*(const float4*)p, *(const float4*)(p + 4));
      }
    } else {
      #pragma unroll
      for (int j = 0; j < 4; ++j)
        bs8[j] = ld_bf8(Bgh + (size_t)j * 32 * K + kt * 64);
    }
    __syncthreads();
    #pragma unroll
    for (int j = 0; j < 4; ++j) {
      st_bf8(&As[(j * 32 + row_in) * 64 + col_in], as8[j]);
      st_bf8(&Bs[(j * 32 + row_in) * 64 + col_in], bs8[j]);
    }
    __syncthreads();
    #pragma unroll
    for (int ks = 0; ks < 2; ++ks) {
      bf16x8 af[4], bfr[4];
      #pragma unroll
      for (int mt = 0; mt < 4; ++mt)
        af[mt] = ld_bf8(&As[(wm + mt * 16 + l16) * 64 + ks * 32 + quad * 8]);
      #pragma unroll
      for (int nt = 0; nt < 4; ++nt)
        bfr[nt] = ld_bf8(&Bs[(wn + nt * 16 + l16) * 64 + ks * 32 + quad * 8]);
      #pragma unroll
      for (int mt = 0; mt < 4; ++mt)
        #pragma unroll
        for (int nt = 0; nt < 4; ++nt)
          acc[mt][nt] = __builtin_amdgcn_mfma_f32_16x16x32_bf16(af[mt], bfr[nt], acc[mt][nt], 0, 0, 0);
    }
  }
  #pragma unroll
  for (int mt = 0; mt < 4; ++mt) {
    #pragma unroll
    for (int nt = 0; nt < 4; ++nt) {
      const int n = n0 + wn + nt * 16 + l16;
      #pragma unroll
      for (int r = 0; r < 4; ++r) {
        const int m = m0 + wm + mt * 16 + quad * 4 + r;
        if (mode == 0) {
          Cout[(size_t)m * N + n] = acc[mt][nt][r];   // fp32 output
        } else {
          const unsigned short val = f2bf(acc[mt][nt][r]);
          const int b = m >> 11, t = m & (T_SEQ - 1);
          const int which = n >> 10, c = n & 1023;
          const int h = c >> 6, d = c & 63;
          const int bh = b * NHEAD + h;
          if (which == 0)      qb[((size_t)bh * T_SEQ + t) * HS + d] = val;
          else if (which == 1) kb[((size_t)bh * T_SEQ + t) * HS + d] = val;
          else                 vtb[((size_t)bh * HS + d) * T_SEQ + t] = val;  // V transposed
        }
      }
    }
  }
}

// f32 -> bf16 elementwise (vectorized), n multiple of 4.
__global__ __launch_bounds__(256) void cvtbuf(const float* __restrict__ src,
                                              unsigned short* __restrict__ dst, int n) {
  const int i = (blockIdx.x * 256 + threadIdx.x) * 4;
  if (i < n) {
    const float4 v = *(const float4*)(src + i);
    ushort4 o;
    o.x = f2bf(v.x); o.y = f2bf(v.y); o.z = f2bf(v.z); o.w = f2bf(v.w);
    *(ushort4*)(dst + i) = o;
  }
}

// Reference's rolled-RoPE; Q additionally pre-scaled by 0.125 (exact pow2)
// so attention skips the 1/sqrt(hs) multiply.
__global__ __launch_bounds__(256, 1) void rope(unsigned short* __restrict__ qb,
                                               unsigned short* __restrict__ kb) {
  const int idx = blockIdx.x * 256 + threadIdx.x;
  const bool isq = idx < 65536;
  const float qs = isq ? 0.125f : 1.0f;
  unsigned short* buf = (isq ? qb : kb) + (size_t)(idx & 65535) * HS;
  const int t = idx & (T_SEQ - 1);
  float x[64];
  #pragma unroll
  for (int j = 0; j < 64; ++j) x[j] = bf2f(buf[j]);
  __asm__ volatile("" ::: "memory");
  float c[32], s[32], er[32];
  #pragma unroll
  for (int i = 0; i < 32; ++i) {
    const float ang = (float)t * exp2f(-0.41524101186092029f * (float)i);
    c[i] = cosf(ang); s[i] = sinf(ang);
  }
  #pragma unroll
  for (int i = 0; i < 32; ++i)
    er[i] = x[2 * i] * c[i] - x[(2 * i + 63) & 63] * s[i];
  #pragma unroll
  for (int i = 0; i < 32; ++i) {
    const float ep = x[2 * i + 1] * c[i] + er[(i + 1) & 31] * s[i];
    buf[2 * i]     = f2bf(er[i] * qs);
    buf[2 * i + 1] = f2bf(ep * qs);
  }
}

// Flash attention v3: S-TRANSPOSED scheme, one wave per block, no LDS.
// QK^T as A=K,B=Q -> S^T D-layout (lane: q=l16, k=quad*4+r).
// Softmax: 15 in-lane ops + 2 cross-quad shuffles. P lands directly in the
// A-layout of mfma_16x16x16 -> PV without any transpose.
__global__ __launch_bounds__(64, 4) void attn(
    const unsigned short* __restrict__ qb, const unsigned short* __restrict__ kb,
    const unsigned short* __restrict__ vt, unsigned short* __restrict__ yb) {
  const int u = blockIdx.x;            // 0..4095
  const int qi = 127 - (u >> 5);       // longest q-tiles first
  const int bh = u & 31;
  const int q0 = qi * 16;
  const int lane = threadIdx.x & 63;
  const int quad = lane >> 4, l16 = lane & 15;

  // Q as B-operand: B[n=q0+l16][kk=d]
  const unsigned short* qptr = qb + ((size_t)bh * T_SEQ + q0 + l16) * HS;
  const bf16x8 bq0 = ld_bf8(qptr + quad * 8);
  const bf16x8 bq1 = ld_bf8(qptr + 32 + quad * 8);

  f32x4 O[4] = {};          // D-layout: q=q0+quad*4+r, d=dg*16+l16
  float m_i = -1e30f, l_i = 0.f;

  const unsigned short* kbase = kb + (size_t)bh * T_SEQ * HS;
  const unsigned short* vbase = vt + (size_t)bh * HS * T_SEQ;
  const int nfull = (q0 >= 63) ? (((q0 - 63) >> 6) + 1) : 0;

  auto pass_body = [&](int k0, bool masked) {
    bf16x8 ak[4][2];
    #pragma unroll
    for (int t = 0; t < 4; ++t) {
      const unsigned short* kp = kbase + (size_t)(k0 + t * 16 + l16) * HS;
      ak[t][0] = ld_bf8(kp + quad * 8);
      ak[t][1] = ld_bf8(kp + 32 + quad * 8);
    }
    short4v vf[4][4];
    #pragma unroll
    for (int t = 0; t < 4; ++t)
      #pragma unroll
      for (int dg = 0; dg < 4; ++dg)
        vf[t][dg] = *(const short4v*)(vbase + (size_t)(dg * 16 + l16) * T_SEQ + k0 + t * 16 + quad * 4);
    f32x4 S[4] = {};
    #pragma unroll
    for (int t = 0; t < 4; ++t) {
      S[t] = __builtin_amdgcn_mfma_f32_16x16x32_bf16(ak[t][0], bq0, S[t], 0, 0, 0);
      S[t] = __builtin_amdgcn_mfma_f32_16x16x32_bf16(ak[t][1], bq1, S[t], 0, 0, 0);
    }
    float sv[16];
    #pragma unroll
    for (int t = 0; t < 4; ++t)
      #pragma unroll
      for (int r = 0; r < 4; ++r) {
        float v = S[t][r];
        if (masked) v = (k0 + t * 16 + quad * 4 + r <= q0 + l16) ? v : -1e30f;
        sv[t * 4 + r] = v;
      }
    float tm = sv[0];
    #pragma unroll
    for (int i = 1; i < 16; ++i) tm = fmaxf(tm, sv[i]);
    tm = fmaxf(tm, __shfl_xor(tm, 16, 64));
    tm = fmaxf(tm, __shfl_xor(tm, 32, 64));
    const float mnew = fmaxf(m_i, tm);
    const float alpha = __expf(m_i - mnew);
    float p[16], rs = 0.f;
    #pragma unroll
    for (int i = 0; i < 16; ++i) { p[i] = __expf(sv[i] - mnew); rs += p[i]; }
    rs += __shfl_xor(rs, 16, 64);
    rs += __shfl_xor(rs, 32, 64);
    l_i = l_i * alpha + rs;
    m_i = mnew;
    short4v pa[4];
    #pragma unroll
    for (int t = 0; t < 4; ++t) {
      short4v f;
      f[0] = (short)f2bf(p[t * 4 + 0]); f[1] = (short)f2bf(p[t * 4 + 1]);
      f[2] = (short)f2bf(p[t * 4 + 2]); f[3] = (short)f2bf(p[t * 4 + 3]);
      pa[t] = f;
    }
    float aD[4];
    #pragma unroll
    for (int r = 0; r < 4; ++r) aD[r] = __shfl(alpha, quad * 4 + r, 64);
    #pragma unroll
    for (int dg = 0; dg < 4; ++dg)
      #pragma unroll
      for (int r = 0; r < 4; ++r) O[dg][r] *= aD[r];
    #pragma unroll
    for (int t = 0; t < 4; ++t)
      #pragma unroll
      for (int dg = 0; dg < 4; ++dg)
        O[dg] = __builtin_amdgcn_mfma_f32_16x16x16bf16_1k(pa[t], vf[t][dg], O[dg], 0, 0, 0);
  };

  for (int k0 = 0; k0 < nfull * 64; k0 += 64) pass_body(k0, false);
  pass_body(nfull * 64, true);   // exactly one masked pass (diag never straddles two)

  const int b = bh >> 4, h = bh & 15;
  float inv[4];
  #pragma unroll
  for (int r = 0; r < 4; ++r)
    inv[r] = 1.0f / fmaxf(__shfl(l_i, quad * 4 + r, 64), 1e-30f);
  #pragma unroll
  for (int r = 0; r < 4; ++r) {
    const int row = q0 + quad * 4 + r;
    #pragma unroll
    for (int dg = 0; dg < 4; ++dg)
      yb[((size_t)b * T_SEQ + row) * 1024 + h * HS + dg * 16 + l16] = f2bf(O[dg][r] * inv[r]);
  }
}

extern "C" void kernel_launch(void* const* d_in, const int* in_sizes, int n_in,
                              void* d_out, int out_size, void* d_ws, size_t ws_size,
                              hipStream_t stream) {
  const float* x      = (const float*)d_in[0];   // FP32 inputs per reference
  const float* w_attn = (const float*)d_in[1];
  const float* w_proj = (const float*)d_in[2];
  float* out = (float*)d_out;                    // FP32 output per reference
  unsigned short* qb = (unsigned short*)d_ws;          // [32][2048][64] bf16, 8 MB
  unsigned short* kb = qb + (size_t)4194304;           // 8 MB
  unsigned short* vt = kb + (size_t)4194304;           // [32][64][2048] transposed, 8 MB
  unsigned short* yb = vt + (size_t)4194304;           // [2][2048][1024] bf16, 8 MB

  if (ws_size >= (size_t)50331648 + (size_t)2097152) {
    // Pre-convert inputs to bf16 once; both GEMMs use the bf16 staging path.
    unsigned short* xb  = yb + (size_t)4194304;        // 4,194,304 elems
    unsigned short* wab = xb + (size_t)4194304;        // 3,145,728 elems
    unsigned short* wpb = wab + (size_t)3145728;       // 1,048,576 elems
    cvtbuf<<<dim3(4096), 256, 0, stream>>>(x, xb, 4194304);
    cvtbuf<<<dim3(3072), 256, 0, stream>>>(w_attn, wab, 3145728);
    cvtbuf<<<dim3(1024), 256, 0, stream>>>(w_proj, wpb, 1048576);
    gemm_bt<<<dim3(24, 32), 256, 0, stream>>>(xb, wab, nullptr, qb, kb, vt,
                                              4096, 3072, 1024, 0, 0, 1);
    rope<<<dim3(512), 256, 0, stream>>>(qb, kb);
    attn<<<dim3(4096), 64, 0, stream>>>(qb, kb, vt, yb);
    gemm_bt<<<dim3(8, 32), 256, 0, stream>>>(yb, wpb, out, nullptr, nullptr, nullptr,
                                             4096, 1024, 1024, 0, 0, 0);
  } else {
    gemm_bt<<<dim3(24, 32), 256, 0, stream>>>(x, w_attn, nullptr, qb, kb, vt,
                                              4096, 3072, 1024, 1, 1, 1);
    rope<<<dim3(512), 256, 0, stream>>>(qb, kb);
    attn<<<dim3(4096), 64, 0, stream>>>(qb, kb, vt, yb);
    gemm_bt<<<dim3(8, 32), 256, 0, stream>>>(yb, w_proj, out, nullptr, nullptr, nullptr,
                                             4096, 1024, 1024, 0, 1, 0);
  }
}

// Round 10
// 352.709 us; speedup vs baseline: 1.0024x; 1.0024x over previous
//
#include <hip/hip_runtime.h>

#define T_SEQ 2048
#define NHEAD 16
#define HS 64

typedef __bf16 bf16x8 __attribute__((ext_vector_type(8)));
typedef float f32x4 __attribute__((ext_vector_type(4)));
typedef short short4v __attribute__((ext_vector_type(4)));

__device__ __forceinline__ unsigned short f2bf(float f) {
  union { float f; unsigned int u; } v; v.f = f;
  return (unsigned short)((v.u + 0x7fffu + ((v.u >> 16) & 1u)) >> 16);
}
__device__ __forceinline__ float bf2f(unsigned short h) {
  union { unsigned int u; float f; } v; v.u = ((unsigned int)h) << 16;
  return v.f;
}
__device__ __forceinline__ bf16x8 ld_bf8(const unsigned short* p) {
  return *(const bf16x8*)p;
}
__device__ __forceinline__ void st_bf8(unsigned short* p, bf16x8 v) {
  *(bf16x8*)p = v;
}
__device__ __forceinline__ bf16x8 cvt8(float4 a, float4 b) {
  bf16x8 r;
  r[0] = (__bf16)a.x; r[1] = (__bf16)a.y; r[2] = (__bf16)a.z; r[3] = (__bf16)a.w;
  r[4] = (__bf16)b.x; r[5] = (__bf16)b.y; r[6] = (__bf16)b.z; r[7] = (__bf16)b.w;
  return r;
}

// C[m,n] = sum_k A[m,k]*B[n,k];  A:[M,K], B:[N,K] row-major.
// af32/bf32: operand element type is float32 (else bf16).
// mode 0: C row-major [M,N] FLOAT32.  mode 1: qkv scatter (N=3072), bf16.
__global__ __launch_bounds__(256, 2) void gemm_bt(
    const void* __restrict__ Av, const void* __restrict__ Bv,
    float* __restrict__ Cout,
    unsigned short* __restrict__ qb, unsigned short* __restrict__ kb,
    unsigned short* __restrict__ vtb,
    int M, int N, int K, int af32, int bf32, int mode) {
  __shared__ unsigned short As[128 * 64];
  __shared__ unsigned short Bs[128 * 64];
  const int tid = threadIdx.x;
  const int wid = tid >> 6, lane = tid & 63;
  const int quad = lane >> 4, l16 = lane & 15;
  const int m0 = blockIdx.y * 128, n0 = blockIdx.x * 128;
  const int wm = (wid >> 1) * 64, wn = (wid & 1) * 64;
  const int row_in = tid >> 3;
  const int col_in = (tid & 7) * 8;
  const float* Agf = (const float*)Av + (size_t)(m0 + row_in) * K + col_in;
  const float* Bgf = (const float*)Bv + (size_t)(n0 + row_in) * K + col_in;
  const unsigned short* Agh = (const unsigned short*)Av + (size_t)(m0 + row_in) * K + col_in;
  const unsigned short* Bgh = (const unsigned short*)Bv + (size_t)(n0 + row_in) * K + col_in;
  f32x4 acc[4][4] = {};
  const int nkt = K >> 6;
  for (int kt = 0; kt < nkt; ++kt) {
    bf16x8 as8[4], bs8[4];
    if (af32) {
      #pragma unroll
      for (int j = 0; j < 4; ++j) {
        const float* p = Agf + (size_t)j * 32 * K + kt * 64;
        as8[j] = cvt8(*(const float4*)p, *(const float4*)(p + 4));
      }
    } else {
      #pragma unroll
      for (int j = 0; j < 4; ++j)
        as8[j] = ld_bf8(Agh + (size_t)j * 32 * K + kt * 64);
    }
    if (bf32) {
      #pragma unroll
      for (int j = 0; j < 4; ++j) {
        const float* p = Bgf + (size_t)j * 32 * K + kt * 64;
        bs8[j] = cvt8(*(const float4*)p, *(const float4*)(p + 4));
      }
    } else {
      #pragma unroll
      for (int j = 0; j < 4; ++j)
        bs8[j] = ld_bf8(Bgh + (size_t)j * 32 * K + kt * 64);
    }
    __syncthreads();
    #pragma unroll
    for (int j = 0; j < 4; ++j) {
      st_bf8(&As[(j * 32 + row_in) * 64 + col_in], as8[j]);
      st_bf8(&Bs[(j * 32 + row_in) * 64 + col_in], bs8[j]);
    }
    __syncthreads();
    #pragma unroll
    for (int ks = 0; ks < 2; ++ks) {
      bf16x8 af[4], bfr[4];
      #pragma unroll
      for (int mt = 0; mt < 4; ++mt)
        af[mt] = ld_bf8(&As[(wm + mt * 16 + l16) * 64 + ks * 32 + quad * 8]);
      #pragma unroll
      for (int nt = 0; nt < 4; ++nt)
        bfr[nt] = ld_bf8(&Bs[(wn + nt * 16 + l16) * 64 + ks * 32 + quad * 8]);
      #pragma unroll
      for (int mt = 0; mt < 4; ++mt)
        #pragma unroll
        for (int nt = 0; nt < 4; ++nt)
          acc[mt][nt] = __builtin_amdgcn_mfma_f32_16x16x32_bf16(af[mt], bfr[nt], acc[mt][nt], 0, 0, 0);
    }
  }
  #pragma unroll
  for (int mt = 0; mt < 4; ++mt) {
    #pragma unroll
    for (int nt = 0; nt < 4; ++nt) {
      const int n = n0 + wn + nt * 16 + l16;
      #pragma unroll
      for (int r = 0; r < 4; ++r) {
        const int m = m0 + wm + mt * 16 + quad * 4 + r;
        if (mode == 0) {
          Cout[(size_t)m * N + n] = acc[mt][nt][r];   // fp32 output
        } else {
          const unsigned short val = f2bf(acc[mt][nt][r]);
          const int b = m >> 11, t = m & (T_SEQ - 1);
          const int which = n >> 10, c = n & 1023;
          const int h = c >> 6, d = c & 63;
          const int bh = b * NHEAD + h;
          if (which == 0)      qb[((size_t)bh * T_SEQ + t) * HS + d] = val;
          else if (which == 1) kb[((size_t)bh * T_SEQ + t) * HS + d] = val;
          else                 vtb[((size_t)bh * HS + d) * T_SEQ + t] = val;  // V transposed
        }
      }
    }
  }
}

// f32 -> bf16 elementwise (vectorized), n multiple of 4.
__global__ __launch_bounds__(256) void cvtbuf(const float* __restrict__ src,
                                              unsigned short* __restrict__ dst, int n) {
  const int i = (blockIdx.x * 256 + threadIdx.x) * 4;
  if (i < n) {
    const float4 v = *(const float4*)(src + i);
    ushort4 o;
    o.x = f2bf(v.x); o.y = f2bf(v.y); o.z = f2bf(v.z); o.w = f2bf(v.w);
    *(ushort4*)(dst + i) = o;
  }
}

// Reference's rolled-RoPE; Q additionally pre-scaled by 0.125 (exact pow2)
// so attention skips the 1/sqrt(hs) multiply.
__global__ __launch_bounds__(256, 1) void rope(unsigned short* __restrict__ qb,
                                               unsigned short* __restrict__ kb) {
  const int idx = blockIdx.x * 256 + threadIdx.x;
  const bool isq = idx < 65536;
  const float qs = isq ? 0.125f : 1.0f;
  unsigned short* buf = (isq ? qb : kb) + (size_t)(idx & 65535) * HS;
  const int t = idx & (T_SEQ - 1);
  float x[64];
  #pragma unroll
  for (int j = 0; j < 64; ++j) x[j] = bf2f(buf[j]);
  __asm__ volatile("" ::: "memory");
  float c[32], s[32], er[32];
  #pragma unroll
  for (int i = 0; i < 32; ++i) {
    const float ang = (float)t * exp2f(-0.41524101186092029f * (float)i);
    c[i] = cosf(ang); s[i] = sinf(ang);
  }
  #pragma unroll
  for (int i = 0; i < 32; ++i)
    er[i] = x[2 * i] * c[i] - x[(2 * i + 63) & 63] * s[i];
  #pragma unroll
  for (int i = 0; i < 32; ++i) {
    const float ep = x[2 * i + 1] * c[i] + er[(i + 1) & 31] * s[i];
    buf[2 * i]     = f2bf(er[i] * qs);
    buf[2 * i + 1] = f2bf(ep * qs);
  }
}

// Flash attention v4: S-transposed scheme + intra-block K-split.
// Block = 4 waves (256 thr) on ONE (bh, 16-row q-tile); wave w takes passes
// p = w, w+4, ... (online softmax is order-independent); partials merged in LDS:
// m* = max m_w; O* = sum O_w e^(m_w-m*); l* = sum l_w e^(m_w-m*). Empty waves
// contribute exactly 0. 16 blocks/CU -> 32 waves/CU (2x round 9).
__global__ __launch_bounds__(256, 4) void attn(
    const unsigned short* __restrict__ qb, const unsigned short* __restrict__ kb,
    const unsigned short* __restrict__ vt, unsigned short* __restrict__ yb) {
  __shared__ float Om[4][16][64];
  __shared__ float Ml[4][2][16];
  const int u = blockIdx.x;            // 0..4095
  const int qi = 127 - (u >> 5);       // longest q-tiles first
  const int bh = u & 31;
  const int q0 = qi * 16;
  const int wid = threadIdx.x >> 6;
  const int lane = threadIdx.x & 63;
  const int quad = lane >> 4, l16 = lane & 15;

  // Q as B-operand: B[n=q0+l16][kk=d]  (Q pre-scaled by 0.125 in rope)
  const unsigned short* qptr = qb + ((size_t)bh * T_SEQ + q0 + l16) * HS;
  const bf16x8 bq0 = ld_bf8(qptr + quad * 8);
  const bf16x8 bq1 = ld_bf8(qptr + 32 + quad * 8);

  f32x4 O[4] = {};          // D-layout: q=q0+quad*4+r, d=dg*16+l16
  float m_i = -1e30f, l_i = 0.f;

  const unsigned short* kbase = kb + (size_t)bh * T_SEQ * HS;
  const unsigned short* vbase = vt + (size_t)bh * HS * T_SEQ;
  const int P = (q0 + 16 + 63) >> 6;   // number of 64-wide passes

  for (int p = wid; p < P; p += 4) {
    const int k0 = p * 64;
    const bool masked = (p == P - 1);
    bf16x8 ak[4][2];
    #pragma unroll
    for (int t = 0; t < 4; ++t) {
      const unsigned short* kp = kbase + (size_t)(k0 + t * 16 + l16) * HS;
      ak[t][0] = ld_bf8(kp + quad * 8);
      ak[t][1] = ld_bf8(kp + 32 + quad * 8);
    }
    short4v vf[4][4];
    #pragma unroll
    for (int t = 0; t < 4; ++t)
      #pragma unroll
      for (int dg = 0; dg < 4; ++dg)
        vf[t][dg] = *(const short4v*)(vbase + (size_t)(dg * 16 + l16) * T_SEQ + k0 + t * 16 + quad * 4);
    f32x4 S[4] = {};
    #pragma unroll
    for (int t = 0; t < 4; ++t) {
      S[t] = __builtin_amdgcn_mfma_f32_16x16x32_bf16(ak[t][0], bq0, S[t], 0, 0, 0);
      S[t] = __builtin_amdgcn_mfma_f32_16x16x32_bf16(ak[t][1], bq1, S[t], 0, 0, 0);
    }
    float sv[16];
    #pragma unroll
    for (int t = 0; t < 4; ++t)
      #pragma unroll
      for (int r = 0; r < 4; ++r) {
        float v = S[t][r];
        if (masked) v = (k0 + t * 16 + quad * 4 + r <= q0 + l16) ? v : -1e30f;
        sv[t * 4 + r] = v;
      }
    float tm = sv[0];
    #pragma unroll
    for (int i = 1; i < 16; ++i) tm = fmaxf(tm, sv[i]);
    tm = fmaxf(tm, __shfl_xor(tm, 16, 64));
    tm = fmaxf(tm, __shfl_xor(tm, 32, 64));
    const float mnew = fmaxf(m_i, tm);
    const float alpha = __expf(m_i - mnew);
    float p16[16], rs = 0.f;
    #pragma unroll
    for (int i = 0; i < 16; ++i) { p16[i] = __expf(sv[i] - mnew); rs += p16[i]; }
    rs += __shfl_xor(rs, 16, 64);
    rs += __shfl_xor(rs, 32, 64);
    l_i = l_i * alpha + rs;
    m_i = mnew;
    short4v pa[4];
    #pragma unroll
    for (int t = 0; t < 4; ++t) {
      short4v f;
      f[0] = (short)f2bf(p16[t * 4 + 0]); f[1] = (short)f2bf(p16[t * 4 + 1]);
      f[2] = (short)f2bf(p16[t * 4 + 2]); f[3] = (short)f2bf(p16[t * 4 + 3]);
      pa[t] = f;
    }
    float aD[4];
    #pragma unroll
    for (int r = 0; r < 4; ++r) aD[r] = __shfl(alpha, quad * 4 + r, 64);
    #pragma unroll
    for (int dg = 0; dg < 4; ++dg)
      #pragma unroll
      for (int r = 0; r < 4; ++r) O[dg][r] *= aD[r];
    #pragma unroll
    for (int t = 0; t < 4; ++t)
      #pragma unroll
      for (int dg = 0; dg < 4; ++dg)
        O[dg] = __builtin_amdgcn_mfma_f32_16x16x16bf16_1k(pa[t], vf[t][dg], O[dg], 0, 0, 0);
  }

  // Publish partials (m,l replicated across quads; quad 0 writes).
  if (quad == 0) { Ml[wid][0][l16] = m_i; Ml[wid][1][l16] = l_i; }
  #pragma unroll
  for (int dg = 0; dg < 4; ++dg)
    #pragma unroll
    for (int r = 0; r < 4; ++r)
      Om[wid][quad * 4 + r][dg * 16 + l16] = O[dg][r];
  __syncthreads();
  if (wid != 0) return;

  const int b = bh >> 4, h = bh & 15;
  #pragma unroll
  for (int r = 0; r < 4; ++r) {
    const int row = quad * 4 + r;
    float mw[4];
    #pragma unroll
    for (int w = 0; w < 4; ++w) mw[w] = Ml[w][0][row];
    const float ms = fmaxf(fmaxf(mw[0], mw[1]), fmaxf(mw[2], mw[3]));
    float fw[4], ls = 0.f;
    #pragma unroll
    for (int w = 0; w < 4; ++w) { fw[w] = __expf(mw[w] - ms); ls += fw[w] * Ml[w][1][row]; }
    const float inv = 1.0f / fmaxf(ls, 1e-30f);
    #pragma unroll
    for (int dg = 0; dg < 4; ++dg) {
      float ov = 0.f;
      #pragma unroll
      for (int w = 0; w < 4; ++w) ov += Om[w][row][dg * 16 + l16] * fw[w];
      yb[((size_t)b * T_SEQ + q0 + row) * 1024 + h * HS + dg * 16 + l16] = f2bf(ov * inv);
    }
  }
}

extern "C" void kernel_launch(void* const* d_in, const int* in_sizes, int n_in,
                              void* d_out, int out_size, void* d_ws, size_t ws_size,
                              hipStream_t stream) {
  const float* x      = (const float*)d_in[0];   // FP32 inputs per reference
  const float* w_attn = (const float*)d_in[1];
  const float* w_proj = (const float*)d_in[2];
  float* out = (float*)d_out;                    // FP32 output per reference
  unsigned short* qb = (unsigned short*)d_ws;          // [32][2048][64] bf16, 8 MB
  unsigned short* kb = qb + (size_t)4194304;           // 8 MB
  unsigned short* vt = kb + (size_t)4194304;           // [32][64][2048] transposed, 8 MB
  unsigned short* yb = vt + (size_t)4194304;           // [2][2048][1024] bf16, 8 MB

  if (ws_size >= (size_t)50331648 + (size_t)2097152) {
    // Pre-convert inputs to bf16 once; both GEMMs use the bf16 staging path.
    unsigned short* xb  = yb + (size_t)4194304;
    unsigned short* wab = xb + (size_t)4194304;
    unsigned short* wpb = wab + (size_t)3145728;
    cvtbuf<<<dim3(4096), 256, 0, stream>>>(x, xb, 4194304);
    cvtbuf<<<dim3(3072), 256, 0, stream>>>(w_attn, wab, 3145728);
    cvtbuf<<<dim3(1024), 256, 0, stream>>>(w_proj, wpb, 1048576);
    gemm_bt<<<dim3(24, 32), 256, 0, stream>>>(xb, wab, nullptr, qb, kb, vt,
                                              4096, 3072, 1024, 0, 0, 1);
    rope<<<dim3(512), 256, 0, stream>>>(qb, kb);
    attn<<<dim3(4096), 256, 0, stream>>>(qb, kb, vt, yb);
    gemm_bt<<<dim3(8, 32), 256, 0, stream>>>(yb, wpb, out, nullptr, nullptr, nullptr,
                                             4096, 1024, 1024, 0, 0, 0);
  } else {
    gemm_bt<<<dim3(24, 32), 256, 0, stream>>>(x, w_attn, nullptr, qb, kb, vt,
                                              4096, 3072, 1024, 1, 1, 1);
    rope<<<dim3(512), 256, 0, stream>>>(qb, kb);
    attn<<<dim3(4096), 256, 0, stream>>>(qb, kb, vt, yb);
    gemm_bt<<<dim3(8, 32), 256, 0, stream>>>(yb, w_proj, out, nullptr, nullptr, nullptr,
                                             4096, 1024, 1024, 0, 1, 0);
  }
}